// Round 10
// baseline (88.937 us; speedup 1.0000x reference)
//
#include <hip/hip_runtime.h>

#define NN 2048
#define KK 512

typedef __attribute__((ext_vector_type(8))) short bf16x8;
typedef __attribute__((ext_vector_type(4))) float f32x4;

__device__ inline ushort f2bf(float x) {  // RNE f32->bf16
  union { float f; unsigned u; } v; v.f = x;
  unsigned r = v.u + 0x7fffu + ((v.u >> 16) & 1u);
  return (ushort)(r >> 16);
}

// -------- K0: W -> WT_hi/WT_lo (bf16 split, [n][k] layout). grid 32 --------
__global__ __launch_bounds__(256) void k_wprep(
    const float* __restrict__ W, ushort* __restrict__ wthi,
    ushort* __restrict__ wtlo) {
  __shared__ float ts[64][65];
  const int t = threadIdx.x;
  const int kb = (blockIdx.x >> 2) * 64;
  const int nb = (blockIdx.x & 3) * 64;
  const int r = t >> 6, c = t & 63;
#pragma unroll
  for (int p = 0; p < 16; ++p)
    ts[p * 4 + r][c] = W[(size_t)(kb + p * 4 + r) * 256 + nb + c];
  __syncthreads();
#pragma unroll
  for (int p = 0; p < 16; ++p) {
    int n = p * 4 + r;
    int k = c;
    float v = ts[k][n];
    union { float f; unsigned u; } q; q.f = v;
    ushort hi = (ushort)(q.u >> 16);
    union { float f; unsigned u; } hf; hf.u = q.u & 0xffff0000u;
    ushort lo = f2bf(v - hf.f);
    size_t off = (size_t)(nb + n) * KK + kb + k;
    wthi[off] = hi;
    wtlo[off] = lo;
  }
}

// -------- K1: g = h@W via split-bf16 MFMA; writes gTb + exp tables ---------
// grid 128 (16 rows each), block 256 (wave = head). Proven R6-R9, unchanged.
__global__ __launch_bounds__(256) void k_gemm(
    const float* __restrict__ hin, const ushort* __restrict__ wthi,
    const ushort* __restrict__ wtlo, const float* __restrict__ aw,
    ushort* __restrict__ gTb,
    float* __restrict__ Eel, float* __restrict__ Fel,
    float* __restrict__ Eer_jh, float* __restrict__ Fer_jh,
    float* __restrict__ Eer_hj, float* __restrict__ Fer_hj) {
  __shared__ float hs[16][516];
  const int tid = threadIdx.x;
  const int i0 = blockIdx.x * 16;
#pragma unroll
  for (int p = 0; p < 8; ++p) {
    int g4 = tid + p * 256;
    int row = g4 >> 7, col = (g4 & 127) << 2;
    *(float4*)&hs[row][col] = *(const float4*)(hin + (size_t)(i0 + row) * KK + col);
  }
  __syncthreads();

  const int h = tid >> 6;
  const int lane = tid & 63;
  const int il = lane & 15;
  const int kg = lane >> 4;

  f32x4 acc[4];
#pragma unroll
  for (int nt = 0; nt < 4; ++nt) acc[nt] = (f32x4){0.f, 0.f, 0.f, 0.f};

  const ushort* bh_base = wthi + (size_t)(h * 64 + il) * KK;
  const ushort* bl_base = wtlo + (size_t)(h * 64 + il) * KK;

#pragma unroll 4
  for (int ks = 0; ks < 16; ++ks) {
    const int ko = ks * 32 + kg * 8;
    float4 a01 = *(const float4*)&hs[il][ko];
    float4 a23 = *(const float4*)&hs[il][ko + 4];
    float av[8] = {a01.x, a01.y, a01.z, a01.w, a23.x, a23.y, a23.z, a23.w};
    union { unsigned u[4]; bf16x8 v; } Ah, Al;
#pragma unroll
    for (int p = 0; p < 4; ++p) {
      union { float f; unsigned u; } u0, u1;
      u0.f = av[2 * p]; u1.f = av[2 * p + 1];
      Ah.u[p] = (u0.u >> 16) | (u1.u & 0xffff0000u);
      union { float f; unsigned u; } h0, h1;
      h0.u = u0.u & 0xffff0000u;
      h1.u = u1.u & 0xffff0000u;
      union { float f; unsigned u; } r0, r1;
      r0.f = av[2 * p] - h0.f;
      r1.f = av[2 * p + 1] - h1.f;
      Al.u[p] = (r0.u >> 16) | (r1.u & 0xffff0000u);
    }
#pragma unroll
    for (int nt = 0; nt < 4; ++nt) {
      bf16x8 Bh = *(const bf16x8*)(bh_base + nt * 16 * KK + ko);
      bf16x8 Bl = *(const bf16x8*)(bl_base + nt * 16 * KK + ko);
      acc[nt] = __builtin_amdgcn_mfma_f32_16x16x32_bf16(Ah.v, Bh, acc[nt], 0, 0, 0);
      acc[nt] = __builtin_amdgcn_mfma_f32_16x16x32_bf16(Al.v, Bh, acc[nt], 0, 0, 0);
      acc[nt] = __builtin_amdgcn_mfma_f32_16x16x32_bf16(Ah.v, Bl, acc[nt], 0, 0, 0);
    }
  }

  // gTb write: layout [j/8][f][8] bf16
  const int jb = (i0 >> 3) + (kg >> 1);
  const int halfoff = (kg & 1) * 4;
#pragma unroll
  for (int nt = 0; nt < 4; ++nt) {
    const int f = h * 64 + nt * 16 + il;
    unsigned w0 = (unsigned)f2bf(acc[nt][0]) | ((unsigned)f2bf(acc[nt][1]) << 16);
    unsigned w1 = (unsigned)f2bf(acc[nt][2]) | ((unsigned)f2bf(acc[nt][3]) << 16);
    uint2 pk = make_uint2(w0, w1);
    *(uint2*)(gTb + (size_t)jb * 2048 + f * 8 + halfoff) = pk;
  }

  // el/er epilogue -> exp tables directly
  float ela[4] = {0.f, 0.f, 0.f, 0.f}, era[4] = {0.f, 0.f, 0.f, 0.f};
#pragma unroll
  for (int nt = 0; nt < 4; ++nt) {
    float as = aw[nt * 16 + il];
    float ad = aw[64 + nt * 16 + il];
#pragma unroll
    for (int q = 0; q < 4; ++q) {
      ela[q] += acc[nt][q] * as;
      era[q] += acc[nt][q] * ad;
    }
  }
#pragma unroll
  for (int m = 1; m < 16; m <<= 1) {
#pragma unroll
    for (int q = 0; q < 4; ++q) {
      ela[q] += __shfl_xor(ela[q], m);
      era[q] += __shfl_xor(era[q], m);
    }
  }
  if (il == 0) {
#pragma unroll
    for (int q = 0; q < 4; ++q) {
      const int row = i0 + kg * 4 + q;
      float eel = __expf(ela[q]);
      float fel = __expf(0.2f * ela[q]);
      float eer = __expf(era[q]);
      float fer = __expf(0.2f * era[q]);
      Eel[row * 4 + h] = eel;
      Fel[row * 4 + h] = fel;
      Eer_jh[row * 4 + h] = eer;
      Fer_jh[row * 4 + h] = fer;
      Eer_hj[h * NN + row] = eer;
      Fer_hj[h * NN + row] = fer;
    }
  }
}

// -------- K2: mega kernel — Z-pass + coefficients + MFMA + finalize --------
// grid 256 (8 rows/block), block 512 (8 waves).
// Phase 1: wave = row (0..7), full j sweep: mask, exp(s), Z1[h], Z2.
// Phase 2: wave = (head h = w&3, j-half jh = w>>2): proven MFMA loop;
//          A-rows 8..15 are discarded duplicates of rows 0..7.
__global__ __launch_bounds__(512, 2) void k_mega(
    const float* __restrict__ adj, const float* __restrict__ s,
    const ushort* __restrict__ gTb,
    const float* __restrict__ Eel, const float* __restrict__ Fel,
    const float* __restrict__ Eer_jh, const float* __restrict__ Fer_jh,
    const float* __restrict__ Eer_hj, const float* __restrict__ Fer_hj,
    float* __restrict__ out) {
  __shared__ float es_s[8][2052];                 // exp(s), masked (0 if !nb)
  __shared__ unsigned long long maskl[8][34];     // [row][j/64]
  __shared__ float zrow[8][8];                    // [row][h]=1/Z1h, [row][4]=1/Z2
  __shared__ float z3L[2][4][8];                  // [jh][h][row]
  __shared__ float dacc[2][4][8][64];             // [jh][h][row][f]

  const int tid = threadIdx.x;
  const int w = tid >> 6;
  const int lane = tid & 63;
  const int i0 = blockIdx.x * 8;

  // ---------------- phase 1: wave w owns row i0+w ----------------
  {
    const int row = i0 + w;
    const float* ap = adj + (size_t)row * NN;
    const float* sp = s + (size_t)row * NN;
    float4 e4 = *(const float4*)(Eel + row * 4);
    float4 f4 = *(const float4*)(Fel + row * 4);
    const float eel[4] = {e4.x, e4.y, e4.z, e4.w};
    const float fel[4] = {f4.x, f4.y, f4.z, f4.w};
    float z1[4] = {0.f, 0.f, 0.f, 0.f};
    float z2 = 0.f;
#pragma unroll 4
    for (int it = 0; it < 32; ++it) {
      const int j = it * 64 + lane;
      float a = ap[j];
      float sv = sp[j];
      bool nb = (a != 0.f);
      unsigned long long m = __ballot(nb);
      if (lane == 0) maskl[w][it] = m;
      float es = nb ? __expf(sv) : 0.f;
      es_s[w][j] = es;
      z2 += es;
      float4 eer4 = *(const float4*)(Eer_jh + j * 4);
      float4 fer4 = *(const float4*)(Fer_jh + j * 4);
      float ev[4] = {eer4.x, eer4.y, eer4.z, eer4.w};
      float fv[4] = {fer4.x, fer4.y, fer4.z, fer4.w};
#pragma unroll
      for (int h = 0; h < 4; ++h) {
        float E = fmaxf(eel[h] * ev[h], fel[h] * fv[h]);
        z1[h] += nb ? E : 0.f;
      }
    }
#pragma unroll
    for (int m = 1; m < 64; m <<= 1) {
      z2 += __shfl_xor(z2, m);
#pragma unroll
      for (int h = 0; h < 4; ++h) z1[h] += __shfl_xor(z1[h], m);
    }
    if (lane == 0) {
#pragma unroll
      for (int h = 0; h < 4; ++h) zrow[w][h] = 1.f / z1[h];
      zrow[w][4] = 1.f / z2;
    }
  }
  __syncthreads();

  // ---------------- phase 2: wave = (head, j-half) ----------------
  const int h = w & 3;
  const int jh = w >> 2;
  const int il = lane & 15;
  const int kg = lane >> 4;
  const int r = il & 7;             // real row (il>=8: duplicate, discarded)
  const int row = i0 + r;

  const float rz1 = zrow[r][h];
  const float rz2 = zrow[r][4];
  const float eelz = Eel[row * 4 + h] * rz1;
  const float felz = Fel[row * 4 + h] * rz1;

  f32x4 acc[4];
#pragma unroll
  for (int nt = 0; nt < 4; ++nt) acc[nt] = (f32x4){0.f, 0.f, 0.f, 0.f};
  float z3 = 0.f;

  const ushort* bp = gTb + (size_t)(jh * 128 + kg) * 2048 + (h * 64 + il) * 8;
  const float* eerp = Eer_hj + h * NN + jh * 1024 + kg * 8;
  const float* ferp = Fer_hj + h * NN + jh * 1024 + kg * 8;

#pragma unroll 4
  for (int ks = 0; ks < 32; ++ks) {
    const ushort* bks = bp + (size_t)(ks * 4) * 2048;
    bf16x8 B0 = *(const bf16x8*)(bks);
    bf16x8 B1 = *(const bf16x8*)(bks + 128);
    bf16x8 B2 = *(const bf16x8*)(bks + 256);
    bf16x8 B3 = *(const bf16x8*)(bks + 384);

    unsigned long long mw = maskl[r][jh * 16 + (ks >> 1)];
    unsigned byte_ = (unsigned)(mw >> ((ks & 1) * 32 + kg * 8)) & 0xffu;
    const int jl = jh * 1024 + ks * 32 + kg * 8;
    const int go = ks * 32;

    bf16x8 A;
#pragma unroll
    for (int e = 0; e < 8; ++e) {
      bool nb = (byte_ >> e) & 1u;
      float p = eelz * eerp[go + e];
      float q = felz * ferp[go + e];
      float tt = nb ? (fmaxf(p, q) + es_s[r][jl + e] * rz2) : 0.f;
      float c = __expf(tt);
      z3 += c;
      A[e] = (short)f2bf(c);
    }

    acc[0] = __builtin_amdgcn_mfma_f32_16x16x32_bf16(A, B0, acc[0], 0, 0, 0);
    acc[1] = __builtin_amdgcn_mfma_f32_16x16x32_bf16(A, B1, acc[1], 0, 0, 0);
    acc[2] = __builtin_amdgcn_mfma_f32_16x16x32_bf16(A, B2, acc[2], 0, 0, 0);
    acc[3] = __builtin_amdgcn_mfma_f32_16x16x32_bf16(A, B3, acc[3], 0, 0, 0);
  }

  // z3: reduce over kg groups; lanes 0..7 hold rows 0..7 for (jh,h)
  z3 += __shfl_xor(z3, 16);
  z3 += __shfl_xor(z3, 32);
  if (lane < 8) z3L[jh][h][lane] = z3;

  // D-tile store: valid rows i = kg*4+q < 8 (kg<2); cols f = nt*16+il
  if (kg < 2) {
#pragma unroll
    for (int nt = 0; nt < 4; ++nt)
#pragma unroll
      for (int q = 0; q < 4; ++q)
        dacc[jh][h][kg * 4 + q][nt * 16 + il] = acc[nt][q];
  }
  __syncthreads();

  // ---------------- finalize: combine halves, divide, write ----------------
#pragma unroll
  for (int p = 0; p < 4; ++p) {
    const int v = tid + p * 512;
    const int rr = v >> 8;
    const int c = v & 255;
    const int hh = c >> 6;
    const int f = c & 63;
    float u = dacc[0][hh][rr][f] + dacc[1][hh][rr][f];
    float z = z3L[0][hh][rr] + z3L[1][hh][rr];
    out[(size_t)(i0 + rr) * 256 + c] = u / z;
  }
}

extern "C" void kernel_launch(void* const* d_in, const int* in_sizes, int n_in,
                              void* d_out, int out_size, void* d_ws, size_t ws_size,
                              hipStream_t stream) {
  const float* hin = (const float*)d_in[0];
  const float* adj = (const float*)d_in[1];
  const float* s = (const float*)d_in[2];
  const float* W = (const float*)d_in[3];
  const float* aw = (const float*)d_in[4];
  float* out = (float*)d_out;

  // Workspace (f32 slots) — audited, non-overlapping (1.7 MB total):
  //  Eel     [      0,    8192)
  //  Fel     [   8192,   16384)
  //  Eer_jh  [  16384,   24576)
  //  Fer_jh  [  24576,   32768)
  //  Eer_hj  [  32768,   40960)
  //  Fer_hj  [  40960,   49152)
  //  wthi    [  49152,  114688)   131072 ushort
  //  wtlo    [ 114688,  180224)   131072 ushort
  //  gTb     [ 180224,  442368)   524288 ushort
  float* ws = (float*)d_ws;
  float* Eel    = ws;
  float* Fel    = ws + 8192;
  float* Eer_jh = ws + 16384;
  float* Fer_jh = ws + 24576;
  float* Eer_hj = ws + 32768;
  float* Fer_hj = ws + 40960;
  ushort* wthi  = (ushort*)(ws + 49152);
  ushort* wtlo  = (ushort*)(ws + 114688);
  ushort* gTb   = (ushort*)(ws + 180224);

  k_wprep<<<32, 256, 0, stream>>>(W, wthi, wtlo);
  k_gemm<<<128, 256, 0, stream>>>(hin, wthi, wtlo, aw, gTb, Eel, Fel, Eer_jh, Fer_jh, Eer_hj, Fer_hj);
  k_mega<<<256, 512, 0, stream>>>(adj, s, gTb, Eel, Fel, Eer_jh, Fer_jh, Eer_hj, Fer_hj, out);
}